// Round 8
// baseline (1655.884 us; speedup 1.0000x reference)
//
#include <hip/hip_runtime.h>
#include <math.h>

#define NIMG 50000
#define NKN  8192
#define BB   32
#define DD   512
#define CC   32
#define RR   16
#define KK   8
#define MMAX 384   // max class-bucket size supported (mean 256, sd ~15.7)
#define NR   6     // max KN rows per lane (6*64 = 384 = MMAX)

// ---------------------------------------------------------------- class lists
__global__ __launch_bounds__(256) void build_lists(const int* __restrict__ labels,
                                                   int n, int* __restrict__ cnt,
                                                   int* __restrict__ list, int stride) {
    int i = blockIdx.x * 256 + threadIdx.x;
    if (i < n) {
        int c = labels[i];
        int pos = atomicAdd(&cnt[c], 1);
        list[c * stride + pos] = i;
    }
}

// ---------------------------------------------------------------- sims = Q @ I^T
__global__ __launch_bounds__(256) void sims_kernel(const float* __restrict__ Q,
                                                   const float* __restrict__ I,
                                                   float* __restrict__ S) {
    __shared__ float4 qs[BB * DD / 4];  // 64KB
    for (int i = threadIdx.x; i < BB * DD / 4; i += 256)
        qs[i] = ((const float4*)Q)[i];
    __syncthreads();
    int n = blockIdx.x * 256 + threadIdx.x;
    if (n >= NIMG) return;
    float acc[BB];
#pragma unroll
    for (int b = 0; b < BB; b++) acc[b] = 0.f;
    const float4* row = (const float4*)(I + (size_t)n * DD);
    for (int d4 = 0; d4 < DD / 4; d4++) {
        float4 v = row[d4];
#pragma unroll
        for (int b = 0; b < BB; b++) {
            float4 q = qs[b * (DD / 4) + d4];
            acc[b] += v.x * q.x + v.y * q.y + v.z * q.z + v.w * q.w;
        }
    }
#pragma unroll
    for (int b = 0; b < BB; b++) S[(size_t)b * NIMG + n] = acc[b];
}

// ---------------------------------------------------------------- top-16 images per (b,c)
__global__ __launch_bounds__(256) void topk_img(const float* __restrict__ S,
                                                const int* __restrict__ cnt,
                                                const int* __restrict__ list,
                                                int* __restrict__ t_idx,
                                                float* __restrict__ t_w) {
    int c = blockIdx.x, b = blockIdx.y, tid = threadIdx.x;
    __shared__ float sval[256 * RR];
    __shared__ int   sidx[256 * RR];
    __shared__ float redv[256];
    __shared__ int   redp[256];
    __shared__ float kv[RR];
    __shared__ int   ki[RR];

    float tv[RR]; int ti[RR];
#pragma unroll
    for (int k = 0; k < RR; k++) { tv[k] = -1e30f; ti[k] = 0; }

    int m = cnt[c];
    for (int j = tid; j < m; j += 256) {
        int n = list[c * NIMG + j];
        float v = S[(size_t)b * NIMG + n];
        if (v > tv[RR - 1]) {
            int p = RR - 1;
            while (p > 0 && tv[p - 1] < v) { tv[p] = tv[p - 1]; ti[p] = ti[p - 1]; p--; }
            tv[p] = v; ti[p] = n;
        }
    }
#pragma unroll
    for (int k = 0; k < RR; k++) { sval[tid * RR + k] = tv[k]; sidx[tid * RR + k] = ti[k]; }
    __syncthreads();

    for (int k = 0; k < RR; k++) {
        float bv = -1e30f; int bp = 0;
        for (int j = tid; j < 256 * RR; j += 256)
            if (sval[j] > bv) { bv = sval[j]; bp = j; }
        redv[tid] = bv; redp[tid] = bp;
        __syncthreads();
        for (int s = 128; s > 0; s >>= 1) {
            if (tid < s && redv[tid + s] > redv[tid]) { redv[tid] = redv[tid + s]; redp[tid] = redp[tid + s]; }
            __syncthreads();
        }
        if (tid == 0) { kv[k] = redv[0]; ki[k] = sidx[redp[0]]; sval[redp[0]] = -1e30f; }
        __syncthreads();
    }

    if (tid == 0) {
        float mx = kv[0], s = 0.f, e[RR];
#pragma unroll
        for (int k = 0; k < RR; k++) { e[k] = expf(kv[k] - mx); s += e[k]; }
        float inv = 1.f / s;
        size_t o = ((size_t)(b * CC) + c) * RR;
#pragma unroll
        for (int k = 0; k < RR; k++) { t_w[o + k] = e[k] * inv; t_idx[o + k] = ki[k]; }
    }
}

// ---------------------------------------------------------------- enhanced_images
__global__ __launch_bounds__(256) void img_kernel(const float* __restrict__ Q,
                                                  const float* __restrict__ I,
                                                  const int* __restrict__ t_idx,
                                                  const float* __restrict__ t_w,
                                                  float* __restrict__ out) {
    int c = blockIdx.x, b = blockIdx.y, tid = threadIdx.x;
    __shared__ float w[RR];
    __shared__ int   id[RR];
    if (tid < RR) {
        size_t o = ((size_t)(b * CC) + c) * RR;
        w[tid] = t_w[o + tid]; id[tid] = t_idx[o + tid];
    }
    __syncthreads();
    for (int d = tid; d < DD; d += 256) {
        float acc = 0.f;
#pragma unroll
        for (int r = 0; r < RR; r++) acc += w[r] * I[(size_t)id[r] * DD + d];
        out[((size_t)(b * CC) + c) * DD + d] = 0.5f * (Q[b * DD + d] + acc);
    }
}

// ---------------------------------------------------------------- knowledge v5
// v4 + the REAL spill fix: the top-k r-loop is now fully unrolled, so every
// access to acc[i][r] is compile-time static and acc[6][16] registerizes
// (rule #20: one runtime-indexed access forces the whole array to scratch —
// that was 1.5 GB of scratch writes per dispatch in v3/v4).
__global__ __launch_bounds__(64, 1) void knowledge_kernel(const float* __restrict__ Q,
                                                          const float* __restrict__ I,
                                                          const float* __restrict__ KN,
                                                          const int* __restrict__ kcnt,
                                                          const int* __restrict__ klist,
                                                          const int* __restrict__ t_idx,
                                                          const float* __restrict__ t_w,
                                                          float* __restrict__ outk) {
    int c = blockIdx.x, b = blockIdx.y, lane = threadIdx.x;

    __shared__ float4 simg[RR][DD / 4];   // 32 KB: 16 retrieved image rows
    __shared__ float  s_iw[RR];
    __shared__ int    s_ii[RR];
    __shared__ float  wgt[RR][KK];        // combined weights iw_r * softmax_k
    __shared__ int    kidx[RR][KK];       // selected KN global row indices

    if (lane < RR) {
        size_t o = ((size_t)(b * CC) + c) * RR;
        s_iw[lane] = t_w[o + lane]; s_ii[lane] = t_idx[o + lane];
    }
    __syncthreads();

    // stage 16 image rows: each row = 128 float4, 2 per lane
#pragma unroll
    for (int r = 0; r < RR; r++) {
        const float4* src = (const float4*)(I + (size_t)s_ii[r] * DD);
        simg[r][lane]      = src[lane];
        simg[r][lane + 64] = src[lane + 64];
    }

    int m = kcnt[c]; if (m > MMAX) m = MMAX;
    int nrows = (m + 63) >> 6;  // wave-uniform, <= 6

    // row ids (invalid rows -> row 0; masked out at top-k)
    int rowid[NR];
#pragma unroll
    for (int i = 0; i < NR; i++) {
        int j = i * 64 + lane;
        rowid[i] = (j < m) ? klist[c * NKN + j] : 0;
    }

    float acc[NR][RR];
#pragma unroll
    for (int i = 0; i < NR; i++)
#pragma unroll
        for (int r = 0; r < RR; r++) acc[i][r] = 0.f;

    __syncthreads();

    // ---- scoring
    for (int d4 = 0; d4 < DD / 4; d4++) {
        float4 kv[NR];
#pragma unroll
        for (int i = 0; i < NR; i++)
            if (i < nrows) kv[i] = ((const float4*)(KN + (size_t)rowid[i] * DD))[d4];
#pragma unroll
        for (int r = 0; r < RR; r++) {
            float4 u = simg[r][d4];                     // wave-uniform broadcast
#pragma unroll
            for (int i = 0; i < NR; i++)
                if (i < nrows)
                    acc[i][r] += kv[i].x * u.x + kv[i].y * u.y + kv[i].z * u.z + kv[i].w * u.w;
        }
    }

    // ---- per-r top-8 (wave shuffle argmax, lexicographic) + softmax
    // UNROLLED so acc[i][r] stays static-indexed (the v3/v4 scratch bug).
#pragma unroll
    for (int r = 0; r < RR; r++) {
        int myj = 0;      // lane k (k<8) remembers the k-th winner's class-row j
        float lv[NR]; int lj[NR];
#pragma unroll
        for (int i = 0; i < NR; i++) {
            int j = i * 64 + lane;
            lv[i] = (j < m) ? acc[i][r] : -1e30f;
            lj[i] = j;
        }
        unsigned used = 0;
        float kvv[KK];
#pragma unroll
        for (int k = 0; k < KK; k++) {
            float mv = -1e30f; int mj = 0x7fffffff; int mt = 0;
#pragma unroll
            for (int t = 0; t < NR; t++) {
                bool avail = !(used & (1u << t));
                if (avail && (lv[t] > mv || (lv[t] == mv && lj[t] < mj))) {
                    mv = lv[t]; mj = lj[t]; mt = t;
                }
            }
            int cj = mj;
            for (int off = 32; off > 0; off >>= 1) {
                float ov = __shfl_xor(mv, off);
                int   oj = __shfl_xor(mj, off);
                if (ov > mv || (ov == mv && oj < mj)) { mv = ov; mj = oj; }
            }
            if (cj == mj) used |= (1u << mt);  // owner retires its candidate
            if (lane == k) myj = mj;           // lane k holds winner j for rank k
            kvv[k] = mv;
        }
        // all lanes hold identical kvv[]; lane 0 publishes weights,
        // lanes 0..7 publish the global row index in parallel
        if (lane < KK) kidx[r][lane] = klist[c * NKN + myj];
        if (lane == 0) {
            float e[KK], s = 0.f;
#pragma unroll
            for (int k = 0; k < KK; k++) { e[k] = expf(kvv[k] - kvv[0]); s += e[k]; }
            float wr = s_iw[r] / s;
#pragma unroll
            for (int k = 0; k < KK; k++) wgt[r][k] = e[k] * wr;
        }
    }
    __syncthreads();

    // ---- gather-accumulate: lane handles dims [lane*4..+3] and [256+lane*4..+3]
    float4 a0 = {0.f, 0.f, 0.f, 0.f}, a1 = {0.f, 0.f, 0.f, 0.f};
#pragma unroll 8
    for (int p = 0; p < RR * KK; p++) {
        int r = p >> 3, k = p & 7;
        float w = wgt[r][k];
        const float4* kp = (const float4*)(KN + (size_t)kidx[r][k] * DD);
        float4 v0 = kp[lane], v1 = kp[lane + 64];
        a0.x += w * v0.x; a0.y += w * v0.y; a0.z += w * v0.z; a0.w += w * v0.w;
        a1.x += w * v1.x; a1.y += w * v1.y; a1.z += w * v1.z; a1.w += w * v1.w;
    }
    const float4* q4 = (const float4*)(Q + (size_t)b * DD);
    float4 q0 = q4[lane], q1 = q4[lane + 64];
    float4 o0, o1;
    o0.x = 0.5f * (q0.x + a0.x); o0.y = 0.5f * (q0.y + a0.y);
    o0.z = 0.5f * (q0.z + a0.z); o0.w = 0.5f * (q0.w + a0.w);
    o1.x = 0.5f * (q1.x + a1.x); o1.y = 0.5f * (q1.y + a1.y);
    o1.z = 0.5f * (q1.z + a1.z); o1.w = 0.5f * (q1.w + a1.w);
    float4* out4 = (float4*)(outk + ((size_t)(b * CC) + c) * DD);
    out4[lane]      = o0;
    out4[lane + 64] = o1;
}

// ---------------------------------------------------------------- launch
extern "C" void kernel_launch(void* const* d_in, const int* in_sizes, int n_in,
                              void* d_out, int out_size, void* d_ws, size_t ws_size,
                              hipStream_t stream) {
    const float* Q  = (const float*)d_in[0];
    const float* I  = (const float*)d_in[1];
    const float* KN = (const float*)d_in[2];
    const int* ilab = (const int*)d_in[3];
    const int* klab = (const int*)d_in[4];

    char* ws = (char*)d_ws;
    float* S        = (float*)ws;  ws += (size_t)BB * NIMG * 4;
    int*   img_list = (int*)ws;    ws += (size_t)CC * NIMG * 4;
    int*   kn_list  = (int*)ws;    ws += (size_t)CC * NKN * 4;
    int*   t_idx    = (int*)ws;    ws += (size_t)BB * CC * RR * 4;
    float* t_w      = (float*)ws;  ws += (size_t)BB * CC * RR * 4;
    int*   img_cnt  = (int*)ws;    ws += CC * 4;
    int*   kn_cnt   = (int*)ws;    ws += CC * 4;

    float* out_img = (float*)d_out;
    float* out_kn  = out_img + (size_t)BB * CC * DD;

    hipMemsetAsync(img_cnt, 0, 2 * CC * 4, stream);  // img_cnt + kn_cnt contiguous

    build_lists<<<(NIMG + 255) / 256, 256, 0, stream>>>(ilab, NIMG, img_cnt, img_list, NIMG);
    build_lists<<<(NKN  + 255) / 256, 256, 0, stream>>>(klab, NKN,  kn_cnt,  kn_list,  NKN);
    sims_kernel<<<(NIMG + 255) / 256, 256, 0, stream>>>(Q, I, S);
    topk_img<<<dim3(CC, BB), 256, 0, stream>>>(S, img_cnt, img_list, t_idx, t_w);
    img_kernel<<<dim3(CC, BB), 256, 0, stream>>>(Q, I, t_idx, t_w, (float*)d_out);
    knowledge_kernel<<<dim3(CC, BB), 64, 0, stream>>>(Q, I, KN, kn_cnt, kn_list, t_idx, t_w, out_kn);
}

// Round 10
// 552.471 us; speedup vs baseline: 2.9972x; 2.9972x over previous
//
#include <hip/hip_runtime.h>
#include <math.h>

#define NIMG 50000
#define NKN  8192
#define BB   32
#define DD   512
#define CC   32
#define RR   16
#define KK   8
#define MMAX 384   // max class-bucket size supported (mean 256, sd ~15.7)
#define NR   6     // KN rows per lane (6*64 = 384 = MMAX)

typedef float f16v __attribute__((ext_vector_type(16)));

// ---------------------------------------------------------------- class lists
__global__ __launch_bounds__(256) void build_lists(const int* __restrict__ labels,
                                                   int n, int* __restrict__ cnt,
                                                   int* __restrict__ list, int stride) {
    int i = blockIdx.x * 256 + threadIdx.x;
    if (i < n) {
        int c = labels[i];
        int pos = atomicAdd(&cnt[c], 1);
        list[c * stride + pos] = i;
    }
}

// ---------------------------------------------------------------- sims = Q @ I^T
__global__ __launch_bounds__(256) void sims_kernel(const float* __restrict__ Q,
                                                   const float* __restrict__ I,
                                                   float* __restrict__ S) {
    __shared__ float4 qs[BB * DD / 4];  // 64KB
    for (int i = threadIdx.x; i < BB * DD / 4; i += 256)
        qs[i] = ((const float4*)Q)[i];
    __syncthreads();
    int n = blockIdx.x * 256 + threadIdx.x;
    if (n >= NIMG) return;
    float acc[BB];
#pragma unroll
    for (int b = 0; b < BB; b++) acc[b] = 0.f;
    const float4* row = (const float4*)(I + (size_t)n * DD);
    for (int d4 = 0; d4 < DD / 4; d4++) {
        float4 v = row[d4];
#pragma unroll
        for (int b = 0; b < BB; b++) {
            float4 q = qs[b * (DD / 4) + d4];
            acc[b] += v.x * q.x + v.y * q.y + v.z * q.z + v.w * q.w;
        }
    }
#pragma unroll
    for (int b = 0; b < BB; b++) S[(size_t)b * NIMG + n] = acc[b];
}

// ---------------------------------------------------------------- top-16 images per (b,c)
__global__ __launch_bounds__(256) void topk_img(const float* __restrict__ S,
                                                const int* __restrict__ cnt,
                                                const int* __restrict__ list,
                                                int* __restrict__ t_idx,
                                                float* __restrict__ t_w) {
    int c = blockIdx.x, b = blockIdx.y, tid = threadIdx.x;
    __shared__ float sval[256 * RR];
    __shared__ int   sidx[256 * RR];
    __shared__ float redv[256];
    __shared__ int   redp[256];
    __shared__ float kv[RR];
    __shared__ int   ki[RR];

    float tv[RR]; int ti[RR];
#pragma unroll
    for (int k = 0; k < RR; k++) { tv[k] = -1e30f; ti[k] = 0; }

    int m = cnt[c];
    for (int j = tid; j < m; j += 256) {
        int n = list[c * NIMG + j];
        float v = S[(size_t)b * NIMG + n];
        if (v > tv[RR - 1]) {
            int p = RR - 1;
            while (p > 0 && tv[p - 1] < v) { tv[p] = tv[p - 1]; ti[p] = ti[p - 1]; p--; }
            tv[p] = v; ti[p] = n;
        }
    }
#pragma unroll
    for (int k = 0; k < RR; k++) { sval[tid * RR + k] = tv[k]; sidx[tid * RR + k] = ti[k]; }
    __syncthreads();

    for (int k = 0; k < RR; k++) {
        float bv = -1e30f; int bp = 0;
        for (int j = tid; j < 256 * RR; j += 256)
            if (sval[j] > bv) { bv = sval[j]; bp = j; }
        redv[tid] = bv; redp[tid] = bp;
        __syncthreads();
        for (int s = 128; s > 0; s >>= 1) {
            if (tid < s && redv[tid + s] > redv[tid]) { redv[tid] = redv[tid + s]; redp[tid] = redp[tid + s]; }
            __syncthreads();
        }
        if (tid == 0) { kv[k] = redv[0]; ki[k] = sidx[redp[0]]; sval[redp[0]] = -1e30f; }
        __syncthreads();
    }

    if (tid == 0) {
        float mx = kv[0], s = 0.f, e[RR];
#pragma unroll
        for (int k = 0; k < RR; k++) { e[k] = expf(kv[k] - mx); s += e[k]; }
        float inv = 1.f / s;
        size_t o = ((size_t)(b * CC) + c) * RR;
#pragma unroll
        for (int k = 0; k < RR; k++) { t_w[o + k] = e[k] * inv; t_idx[o + k] = ki[k]; }
    }
}

// ---------------------------------------------------------------- enhanced_images
__global__ __launch_bounds__(256) void img_kernel(const float* __restrict__ Q,
                                                  const float* __restrict__ I,
                                                  const int* __restrict__ t_idx,
                                                  const float* __restrict__ t_w,
                                                  float* __restrict__ out) {
    int c = blockIdx.x, b = blockIdx.y, tid = threadIdx.x;
    __shared__ float w[RR];
    __shared__ int   id[RR];
    if (tid < RR) {
        size_t o = ((size_t)(b * CC) + c) * RR;
        w[tid] = t_w[o + tid]; id[tid] = t_idx[o + tid];
    }
    __syncthreads();
    for (int d = tid; d < DD; d += 256) {
        float acc = 0.f;
#pragma unroll
        for (int r = 0; r < RR; r++) acc += w[r] * I[(size_t)id[r] * DD + d];
        out[((size_t)(b * CC) + c) * DD + d] = 0.5f * (Q[b * DD + d] + acc);
    }
}

// ---------------------------------------------------------------- knowledge v6
// One wave per (b,c); 6 KN rows per lane. ALL hot state is named ext_vector /
// scalar SSA variables (no arrays -> no alloca -> scratch impossible); every
// element subscript is a compile-time literal via macro expansion. This is
// the fix for the v3-v5 1.5GB scratch-spill (VGPR stuck at 132).
__global__ __launch_bounds__(64, 1) void knowledge_kernel(const float* __restrict__ Q,
                                                          const float* __restrict__ I,
                                                          const float* __restrict__ KN,
                                                          const int* __restrict__ kcnt,
                                                          const int* __restrict__ klist,
                                                          const int* __restrict__ t_idx,
                                                          const float* __restrict__ t_w,
                                                          float* __restrict__ outk) {
    int c = blockIdx.x, b = blockIdx.y, lane = threadIdx.x;

    __shared__ float4 simg[RR][DD / 4];   // 32 KB: 16 retrieved image rows
    __shared__ float  s_iw[RR];
    __shared__ int    s_ii[RR];
    __shared__ float  wgt[RR][KK];        // combined weights iw_r * softmax_k
    __shared__ int    kidx[RR][KK];       // selected KN global row indices

    if (lane < RR) {
        size_t o = ((size_t)(b * CC) + c) * RR;
        s_iw[lane] = t_w[o + lane]; s_ii[lane] = t_idx[o + lane];
    }
    __syncthreads();

    // stage 16 image rows: each row = 128 float4, 2 per lane
#pragma unroll
    for (int r = 0; r < RR; r++) {
        const float4* src = (const float4*)(I + (size_t)s_ii[r] * DD);
        simg[r][lane]      = src[lane];
        simg[r][lane + 64] = src[lane + 64];
    }

    int m = kcnt[c]; if (m > MMAX) m = MMAX;

    // 6 owned rows (j = t*64+lane); invalid rows clamp to row 0 (masked later)
    int rid0 = klist[c * NKN + ((0 * 64 + lane) < m ? (0 * 64 + lane) : 0)];
    int rid1 = klist[c * NKN + ((1 * 64 + lane) < m ? (1 * 64 + lane) : 0)];
    int rid2 = klist[c * NKN + ((2 * 64 + lane) < m ? (2 * 64 + lane) : 0)];
    int rid3 = klist[c * NKN + ((3 * 64 + lane) < m ? (3 * 64 + lane) : 0)];
    int rid4 = klist[c * NKN + ((4 * 64 + lane) < m ? (4 * 64 + lane) : 0)];
    int rid5 = klist[c * NKN + ((5 * 64 + lane) < m ? (5 * 64 + lane) : 0)];
    const float4* kp0 = (const float4*)(KN + (size_t)rid0 * DD);
    const float4* kp1 = (const float4*)(KN + (size_t)rid1 * DD);
    const float4* kp2 = (const float4*)(KN + (size_t)rid2 * DD);
    const float4* kp3 = (const float4*)(KN + (size_t)rid3 * DD);
    const float4* kp4 = (const float4*)(KN + (size_t)rid4 * DD);
    const float4* kp5 = (const float4*)(KN + (size_t)rid5 * DD);

    f16v A0 = 0.f, A1 = 0.f, A2 = 0.f, A3 = 0.f, A4 = 0.f, A5 = 0.f;

    __syncthreads();

    // ---- scoring: straight-line, all subscripts literal
#define SC_R(r) { float4 u = simg[r][d4]; \
        A0[r] += k0.x*u.x + k0.y*u.y + k0.z*u.z + k0.w*u.w; \
        A1[r] += k1.x*u.x + k1.y*u.y + k1.z*u.z + k1.w*u.w; \
        A2[r] += k2.x*u.x + k2.y*u.y + k2.z*u.z + k2.w*u.w; \
        A3[r] += k3.x*u.x + k3.y*u.y + k3.z*u.z + k3.w*u.w; \
        A4[r] += k4.x*u.x + k4.y*u.y + k4.z*u.z + k4.w*u.w; \
        A5[r] += k5.x*u.x + k5.y*u.y + k5.z*u.z + k5.w*u.w; }

    for (int d4 = 0; d4 < DD / 4; d4++) {
        float4 k0 = kp0[d4], k1 = kp1[d4], k2 = kp2[d4],
               k3 = kp3[d4], k4 = kp4[d4], k5 = kp5[d4];
        SC_R(0)  SC_R(1)  SC_R(2)  SC_R(3)
        SC_R(4)  SC_R(5)  SC_R(6)  SC_R(7)
        SC_R(8)  SC_R(9)  SC_R(10) SC_R(11)
        SC_R(12) SC_R(13) SC_R(14) SC_R(15)
    }
#undef SC_R

    // ---- per-r top-8 (wave shuffle argmax, lexicographic) + softmax
#define CAND(t) { if (!(used & (1u << t)) && \
                      (lv##t > mv || (lv##t == mv && (t * 64 + lane) < mj))) \
                  { mv = lv##t; mj = t * 64 + lane; mt = t; } }

#define ROUND(k) { \
        float mv = -1e30f; int mj = 0x7fffffff; int mt = -1; \
        CAND(0) CAND(1) CAND(2) CAND(3) CAND(4) CAND(5) \
        int cj = mj; \
        for (int off = 32; off > 0; off >>= 1) { \
            float ov = __shfl_xor(mv, off); \
            int   oj = __shfl_xor(mj, off); \
            if (ov > mv || (ov == mv && oj < mj)) { mv = ov; mj = oj; } \
        } \
        if (cj == mj && mt >= 0) used |= (1u << mt); \
        if (lane == k) myj = mj; \
        kv##k = mv; }

#define TOPK_R(r) { \
        float lv0 = (0 * 64 + lane < m) ? A0[r] : -1e30f; \
        float lv1 = (1 * 64 + lane < m) ? A1[r] : -1e30f; \
        float lv2 = (2 * 64 + lane < m) ? A2[r] : -1e30f; \
        float lv3 = (3 * 64 + lane < m) ? A3[r] : -1e30f; \
        float lv4 = (4 * 64 + lane < m) ? A4[r] : -1e30f; \
        float lv5 = (5 * 64 + lane < m) ? A5[r] : -1e30f; \
        unsigned used = 0; int myj = 0; \
        float kv0, kv1, kv2, kv3, kv4, kv5, kv6, kv7; \
        ROUND(0) ROUND(1) ROUND(2) ROUND(3) \
        ROUND(4) ROUND(5) ROUND(6) ROUND(7) \
        if (lane < KK) kidx[r][lane] = klist[c * NKN + myj]; \
        if (lane == 0) { \
            float e0 = 1.f;                 /* expf(kv0-kv0) */ \
            float e1 = expf(kv1 - kv0), e2 = expf(kv2 - kv0), e3 = expf(kv3 - kv0); \
            float e4 = expf(kv4 - kv0), e5 = expf(kv5 - kv0), e6 = expf(kv6 - kv0); \
            float e7 = expf(kv7 - kv0); \
            float s = e0 + e1 + e2 + e3 + e4 + e5 + e6 + e7; \
            float wr = s_iw[r] / s; \
            wgt[r][0] = e0 * wr; wgt[r][1] = e1 * wr; wgt[r][2] = e2 * wr; \
            wgt[r][3] = e3 * wr; wgt[r][4] = e4 * wr; wgt[r][5] = e5 * wr; \
            wgt[r][6] = e6 * wr; wgt[r][7] = e7 * wr; \
        } }

    TOPK_R(0)  TOPK_R(1)  TOPK_R(2)  TOPK_R(3)
    TOPK_R(4)  TOPK_R(5)  TOPK_R(6)  TOPK_R(7)
    TOPK_R(8)  TOPK_R(9)  TOPK_R(10) TOPK_R(11)
    TOPK_R(12) TOPK_R(13) TOPK_R(14) TOPK_R(15)
#undef TOPK_R
#undef ROUND
#undef CAND

    __syncthreads();

    // ---- gather-accumulate: lane handles dims [lane*4..+3] and [256+lane*4..+3]
    float4 a0 = {0.f, 0.f, 0.f, 0.f}, a1 = {0.f, 0.f, 0.f, 0.f};
#pragma unroll 8
    for (int p = 0; p < RR * KK; p++) {
        int r = p >> 3, k = p & 7;
        float w = wgt[r][k];
        const float4* kp = (const float4*)(KN + (size_t)kidx[r][k] * DD);
        float4 v0 = kp[lane], v1 = kp[lane + 64];
        a0.x += w * v0.x; a0.y += w * v0.y; a0.z += w * v0.z; a0.w += w * v0.w;
        a1.x += w * v1.x; a1.y += w * v1.y; a1.z += w * v1.z; a1.w += w * v1.w;
    }
    const float4* q4 = (const float4*)(Q + (size_t)b * DD);
    float4 q0 = q4[lane], q1 = q4[lane + 64];
    float4 o0, o1;
    o0.x = 0.5f * (q0.x + a0.x); o0.y = 0.5f * (q0.y + a0.y);
    o0.z = 0.5f * (q0.z + a0.z); o0.w = 0.5f * (q0.w + a0.w);
    o1.x = 0.5f * (q1.x + a1.x); o1.y = 0.5f * (q1.y + a1.y);
    o1.z = 0.5f * (q1.z + a1.z); o1.w = 0.5f * (q1.w + a1.w);
    float4* out4 = (float4*)(outk + ((size_t)(b * CC) + c) * DD);
    out4[lane]      = o0;
    out4[lane + 64] = o1;
}

// ---------------------------------------------------------------- launch
extern "C" void kernel_launch(void* const* d_in, const int* in_sizes, int n_in,
                              void* d_out, int out_size, void* d_ws, size_t ws_size,
                              hipStream_t stream) {
    const float* Q  = (const float*)d_in[0];
    const float* I  = (const float*)d_in[1];
    const float* KN = (const float*)d_in[2];
    const int* ilab = (const int*)d_in[3];
    const int* klab = (const int*)d_in[4];

    char* ws = (char*)d_ws;
    float* S        = (float*)ws;  ws += (size_t)BB * NIMG * 4;
    int*   img_list = (int*)ws;    ws += (size_t)CC * NIMG * 4;
    int*   kn_list  = (int*)ws;    ws += (size_t)CC * NKN * 4;
    int*   t_idx    = (int*)ws;    ws += (size_t)BB * CC * RR * 4;
    float* t_w      = (float*)ws;  ws += (size_t)BB * CC * RR * 4;
    int*   img_cnt  = (int*)ws;    ws += CC * 4;
    int*   kn_cnt   = (int*)ws;    ws += CC * 4;

    float* out_img = (float*)d_out;
    float* out_kn  = out_img + (size_t)BB * CC * DD;

    hipMemsetAsync(img_cnt, 0, 2 * CC * 4, stream);  // img_cnt + kn_cnt contiguous

    build_lists<<<(NIMG + 255) / 256, 256, 0, stream>>>(ilab, NIMG, img_cnt, img_list, NIMG);
    build_lists<<<(NKN  + 255) / 256, 256, 0, stream>>>(klab, NKN,  kn_cnt,  kn_list,  NKN);
    sims_kernel<<<(NIMG + 255) / 256, 256, 0, stream>>>(Q, I, S);
    topk_img<<<dim3(CC, BB), 256, 0, stream>>>(S, img_cnt, img_list, t_idx, t_w);
    img_kernel<<<dim3(CC, BB), 256, 0, stream>>>(Q, I, t_idx, t_w, (float*)d_out);
    knowledge_kernel<<<dim3(CC, BB), 64, 0, stream>>>(Q, I, KN, kn_cnt, kn_list, t_idx, t_w, out_kn);
}

// Round 11
// 511.392 us; speedup vs baseline: 3.2380x; 1.0803x over previous
//
#include <hip/hip_runtime.h>
#include <math.h>

#define NIMG 50000
#define NKN  8192
#define BB   32
#define DD   512
#define CC   32
#define RR   16
#define KK   8
#define MMAX 384   // max class-bucket size supported (mean 256, sd ~15.7)
#define NR   6     // KN rows per lane (6*64 = 384 = MMAX)

typedef float f16v __attribute__((ext_vector_type(16)));

// ---------------------------------------------------------------- class lists
__global__ __launch_bounds__(256) void build_lists(const int* __restrict__ labels,
                                                   int n, int* __restrict__ cnt,
                                                   int* __restrict__ list, int stride) {
    int i = blockIdx.x * 256 + threadIdx.x;
    if (i < n) {
        int c = labels[i];
        int pos = atomicAdd(&cnt[c], 1);
        list[c * stride + pos] = i;
    }
}

// ---------------------------------------------------------------- sims = Q @ I^T
__global__ __launch_bounds__(256) void sims_kernel(const float* __restrict__ Q,
                                                   const float* __restrict__ I,
                                                   float* __restrict__ S) {
    __shared__ float4 qs[BB * DD / 4];  // 64KB
    for (int i = threadIdx.x; i < BB * DD / 4; i += 256)
        qs[i] = ((const float4*)Q)[i];
    __syncthreads();
    int n = blockIdx.x * 256 + threadIdx.x;
    if (n >= NIMG) return;
    float acc[BB];
#pragma unroll
    for (int b = 0; b < BB; b++) acc[b] = 0.f;
    const float4* row = (const float4*)(I + (size_t)n * DD);
    for (int d4 = 0; d4 < DD / 4; d4++) {
        float4 v = row[d4];
#pragma unroll
        for (int b = 0; b < BB; b++) {
            float4 q = qs[b * (DD / 4) + d4];
            acc[b] += v.x * q.x + v.y * q.y + v.z * q.z + v.w * q.w;
        }
    }
#pragma unroll
    for (int b = 0; b < BB; b++) S[(size_t)b * NIMG + n] = acc[b];
}

// ---------------------------------------------------------------- top-16 images per (b,c)
__global__ __launch_bounds__(256) void topk_img(const float* __restrict__ S,
                                                const int* __restrict__ cnt,
                                                const int* __restrict__ list,
                                                int* __restrict__ t_idx,
                                                float* __restrict__ t_w) {
    int c = blockIdx.x, b = blockIdx.y, tid = threadIdx.x;
    __shared__ float sval[256 * RR];
    __shared__ int   sidx[256 * RR];
    __shared__ float redv[256];
    __shared__ int   redp[256];
    __shared__ float kv[RR];
    __shared__ int   ki[RR];

    float tv[RR]; int ti[RR];
#pragma unroll
    for (int k = 0; k < RR; k++) { tv[k] = -1e30f; ti[k] = 0; }

    int m = cnt[c];
    for (int j = tid; j < m; j += 256) {
        int n = list[c * NIMG + j];
        float v = S[(size_t)b * NIMG + n];
        if (v > tv[RR - 1]) {
            int p = RR - 1;
            while (p > 0 && tv[p - 1] < v) { tv[p] = tv[p - 1]; ti[p] = ti[p - 1]; p--; }
            tv[p] = v; ti[p] = n;
        }
    }
#pragma unroll
    for (int k = 0; k < RR; k++) { sval[tid * RR + k] = tv[k]; sidx[tid * RR + k] = ti[k]; }
    __syncthreads();

    for (int k = 0; k < RR; k++) {
        float bv = -1e30f; int bp = 0;
        for (int j = tid; j < 256 * RR; j += 256)
            if (sval[j] > bv) { bv = sval[j]; bp = j; }
        redv[tid] = bv; redp[tid] = bp;
        __syncthreads();
        for (int s = 128; s > 0; s >>= 1) {
            if (tid < s && redv[tid + s] > redv[tid]) { redv[tid] = redv[tid + s]; redp[tid] = redp[tid + s]; }
            __syncthreads();
        }
        if (tid == 0) { kv[k] = redv[0]; ki[k] = sidx[redp[0]]; sval[redp[0]] = -1e30f; }
        __syncthreads();
    }

    if (tid == 0) {
        float mx = kv[0], s = 0.f, e[RR];
#pragma unroll
        for (int k = 0; k < RR; k++) { e[k] = expf(kv[k] - mx); s += e[k]; }
        float inv = 1.f / s;
        size_t o = ((size_t)(b * CC) + c) * RR;
#pragma unroll
        for (int k = 0; k < RR; k++) { t_w[o + k] = e[k] * inv; t_idx[o + k] = ki[k]; }
    }
}

// ---------------------------------------------------------------- enhanced_images
__global__ __launch_bounds__(256) void img_kernel(const float* __restrict__ Q,
                                                  const float* __restrict__ I,
                                                  const int* __restrict__ t_idx,
                                                  const float* __restrict__ t_w,
                                                  float* __restrict__ out) {
    int c = blockIdx.x, b = blockIdx.y, tid = threadIdx.x;
    __shared__ float w[RR];
    __shared__ int   id[RR];
    if (tid < RR) {
        size_t o = ((size_t)(b * CC) + c) * RR;
        w[tid] = t_w[o + tid]; id[tid] = t_idx[o + tid];
    }
    __syncthreads();
    for (int d = tid; d < DD; d += 256) {
        float acc = 0.f;
#pragma unroll
        for (int r = 0; r < RR; r++) acc += w[r] * I[(size_t)id[r] * DD + d];
        out[((size_t)(b * CC) + c) * DD + d] = 0.5f * (Q[b * DD + d] + acc);
    }
}

// ---------------------------------------------------------------- knowledge v7
// v6 (named-SSA, no scratch) + T14 2-deep software pipeline in the scoring
// loop: rotating register sets a_k*/b_k* so the 6 scattered KN loads for
// step d4+1 are in flight while the 384 FMAs of step d4 execute. At 1
// wave/SIMD there is no TLP — ILP prefetch is the only latency hiding.
__global__ __launch_bounds__(64, 1) void knowledge_kernel(const float* __restrict__ Q,
                                                          const float* __restrict__ I,
                                                          const float* __restrict__ KN,
                                                          const int* __restrict__ kcnt,
                                                          const int* __restrict__ klist,
                                                          const int* __restrict__ t_idx,
                                                          const float* __restrict__ t_w,
                                                          float* __restrict__ outk) {
    int c = blockIdx.x, b = blockIdx.y, lane = threadIdx.x;

    __shared__ float4 simg[RR][DD / 4];   // 32 KB: 16 retrieved image rows
    __shared__ float  s_iw[RR];
    __shared__ int    s_ii[RR];
    __shared__ float  wgt[RR][KK];        // combined weights iw_r * softmax_k
    __shared__ int    kidx[RR][KK];       // selected KN global row indices

    if (lane < RR) {
        size_t o = ((size_t)(b * CC) + c) * RR;
        s_iw[lane] = t_w[o + lane]; s_ii[lane] = t_idx[o + lane];
    }
    __syncthreads();

    // stage 16 image rows: each row = 128 float4, 2 per lane
#pragma unroll
    for (int r = 0; r < RR; r++) {
        const float4* src = (const float4*)(I + (size_t)s_ii[r] * DD);
        simg[r][lane]      = src[lane];
        simg[r][lane + 64] = src[lane + 64];
    }

    int m = kcnt[c]; if (m > MMAX) m = MMAX;

    // 6 owned rows (j = t*64+lane); invalid rows clamp to row 0 (masked later)
    int rid0 = klist[c * NKN + ((0 * 64 + lane) < m ? (0 * 64 + lane) : 0)];
    int rid1 = klist[c * NKN + ((1 * 64 + lane) < m ? (1 * 64 + lane) : 0)];
    int rid2 = klist[c * NKN + ((2 * 64 + lane) < m ? (2 * 64 + lane) : 0)];
    int rid3 = klist[c * NKN + ((3 * 64 + lane) < m ? (3 * 64 + lane) : 0)];
    int rid4 = klist[c * NKN + ((4 * 64 + lane) < m ? (4 * 64 + lane) : 0)];
    int rid5 = klist[c * NKN + ((5 * 64 + lane) < m ? (5 * 64 + lane) : 0)];
    const float4* kp0 = (const float4*)(KN + (size_t)rid0 * DD);
    const float4* kp1 = (const float4*)(KN + (size_t)rid1 * DD);
    const float4* kp2 = (const float4*)(KN + (size_t)rid2 * DD);
    const float4* kp3 = (const float4*)(KN + (size_t)rid3 * DD);
    const float4* kp4 = (const float4*)(KN + (size_t)rid4 * DD);
    const float4* kp5 = (const float4*)(KN + (size_t)rid5 * DD);

    f16v A0 = 0.f, A1 = 0.f, A2 = 0.f, A3 = 0.f, A4 = 0.f, A5 = 0.f;

    __syncthreads();

    // ---- scoring: 2-deep pipelined, all subscripts literal, all state named
#define SC_R(r, K0, K1, K2, K3, K4, K5, D4) { float4 u = simg[r][D4]; \
        A0[r] += K0.x*u.x + K0.y*u.y + K0.z*u.z + K0.w*u.w; \
        A1[r] += K1.x*u.x + K1.y*u.y + K1.z*u.z + K1.w*u.w; \
        A2[r] += K2.x*u.x + K2.y*u.y + K2.z*u.z + K2.w*u.w; \
        A3[r] += K3.x*u.x + K3.y*u.y + K3.z*u.z + K3.w*u.w; \
        A4[r] += K4.x*u.x + K4.y*u.y + K4.z*u.z + K4.w*u.w; \
        A5[r] += K5.x*u.x + K5.y*u.y + K5.z*u.z + K5.w*u.w; }

#define SC_ALL(K0, K1, K2, K3, K4, K5, D4) \
        SC_R(0,  K0,K1,K2,K3,K4,K5, D4) SC_R(1,  K0,K1,K2,K3,K4,K5, D4) \
        SC_R(2,  K0,K1,K2,K3,K4,K5, D4) SC_R(3,  K0,K1,K2,K3,K4,K5, D4) \
        SC_R(4,  K0,K1,K2,K3,K4,K5, D4) SC_R(5,  K0,K1,K2,K3,K4,K5, D4) \
        SC_R(6,  K0,K1,K2,K3,K4,K5, D4) SC_R(7,  K0,K1,K2,K3,K4,K5, D4) \
        SC_R(8,  K0,K1,K2,K3,K4,K5, D4) SC_R(9,  K0,K1,K2,K3,K4,K5, D4) \
        SC_R(10, K0,K1,K2,K3,K4,K5, D4) SC_R(11, K0,K1,K2,K3,K4,K5, D4) \
        SC_R(12, K0,K1,K2,K3,K4,K5, D4) SC_R(13, K0,K1,K2,K3,K4,K5, D4) \
        SC_R(14, K0,K1,K2,K3,K4,K5, D4) SC_R(15, K0,K1,K2,K3,K4,K5, D4)

    // prologue: load d4=0 into the A set
    float4 ak0 = kp0[0], ak1 = kp1[0], ak2 = kp2[0],
           ak3 = kp3[0], ak4 = kp4[0], ak5 = kp5[0];

    for (int d4 = 0; d4 < DD / 4; d4 += 2) {
        // phase A: prefetch d4+1 into B set, compute with A set
        float4 bk0 = kp0[d4 + 1], bk1 = kp1[d4 + 1], bk2 = kp2[d4 + 1],
               bk3 = kp3[d4 + 1], bk4 = kp4[d4 + 1], bk5 = kp5[d4 + 1];
        SC_ALL(ak0, ak1, ak2, ak3, ak4, ak5, d4)
        // phase B: prefetch d4+2 into A set (clamped tail), compute with B set
        int nx = (d4 + 2 < DD / 4) ? (d4 + 2) : (DD / 4 - 1);
        ak0 = kp0[nx]; ak1 = kp1[nx]; ak2 = kp2[nx];
        ak3 = kp3[nx]; ak4 = kp4[nx]; ak5 = kp5[nx];
        SC_ALL(bk0, bk1, bk2, bk3, bk4, bk5, d4 + 1)
    }
#undef SC_ALL
#undef SC_R

    // ---- per-r top-8 (wave shuffle argmax, lexicographic) + softmax
#define CAND(t) { if (!(used & (1u << t)) && \
                      (lv##t > mv || (lv##t == mv && (t * 64 + lane) < mj))) \
                  { mv = lv##t; mj = t * 64 + lane; mt = t; } }

#define ROUND(k) { \
        float mv = -1e30f; int mj = 0x7fffffff; int mt = -1; \
        CAND(0) CAND(1) CAND(2) CAND(3) CAND(4) CAND(5) \
        int cj = mj; \
        for (int off = 32; off > 0; off >>= 1) { \
            float ov = __shfl_xor(mv, off); \
            int   oj = __shfl_xor(mj, off); \
            if (ov > mv || (ov == mv && oj < mj)) { mv = ov; mj = oj; } \
        } \
        if (cj == mj && mt >= 0) used |= (1u << mt); \
        if (lane == k) myj = mj; \
        kv##k = mv; }

#define TOPK_R(r) { \
        float lv0 = (0 * 64 + lane < m) ? A0[r] : -1e30f; \
        float lv1 = (1 * 64 + lane < m) ? A1[r] : -1e30f; \
        float lv2 = (2 * 64 + lane < m) ? A2[r] : -1e30f; \
        float lv3 = (3 * 64 + lane < m) ? A3[r] : -1e30f; \
        float lv4 = (4 * 64 + lane < m) ? A4[r] : -1e30f; \
        float lv5 = (5 * 64 + lane < m) ? A5[r] : -1e30f; \
        unsigned used = 0; int myj = 0; \
        float kv0, kv1, kv2, kv3, kv4, kv5, kv6, kv7; \
        ROUND(0) ROUND(1) ROUND(2) ROUND(3) \
        ROUND(4) ROUND(5) ROUND(6) ROUND(7) \
        if (lane < KK) kidx[r][lane] = klist[c * NKN + myj]; \
        if (lane == 0) { \
            float e0 = 1.f;                 /* expf(kv0-kv0) */ \
            float e1 = expf(kv1 - kv0), e2 = expf(kv2 - kv0), e3 = expf(kv3 - kv0); \
            float e4 = expf(kv4 - kv0), e5 = expf(kv5 - kv0), e6 = expf(kv6 - kv0); \
            float e7 = expf(kv7 - kv0); \
            float s = e0 + e1 + e2 + e3 + e4 + e5 + e6 + e7; \
            float wr = s_iw[r] / s; \
            wgt[r][0] = e0 * wr; wgt[r][1] = e1 * wr; wgt[r][2] = e2 * wr; \
            wgt[r][3] = e3 * wr; wgt[r][4] = e4 * wr; wgt[r][5] = e5 * wr; \
            wgt[r][6] = e6 * wr; wgt[r][7] = e7 * wr; \
        } }

    TOPK_R(0)  TOPK_R(1)  TOPK_R(2)  TOPK_R(3)
    TOPK_R(4)  TOPK_R(5)  TOPK_R(6)  TOPK_R(7)
    TOPK_R(8)  TOPK_R(9)  TOPK_R(10) TOPK_R(11)
    TOPK_R(12) TOPK_R(13) TOPK_R(14) TOPK_R(15)
#undef TOPK_R
#undef ROUND
#undef CAND

    __syncthreads();

    // ---- gather-accumulate: lane handles dims [lane*4..+3] and [256+lane*4..+3]
    float4 a0 = {0.f, 0.f, 0.f, 0.f}, a1 = {0.f, 0.f, 0.f, 0.f};
#pragma unroll 8
    for (int p = 0; p < RR * KK; p++) {
        int r = p >> 3, k = p & 7;
        float w = wgt[r][k];
        const float4* kp = (const float4*)(KN + (size_t)kidx[r][k] * DD);
        float4 v0 = kp[lane], v1 = kp[lane + 64];
        a0.x += w * v0.x; a0.y += w * v0.y; a0.z += w * v0.z; a0.w += w * v0.w;
        a1.x += w * v1.x; a1.y += w * v1.y; a1.z += w * v1.z; a1.w += w * v1.w;
    }
    const float4* q4 = (const float4*)(Q + (size_t)b * DD);
    float4 q0 = q4[lane], q1 = q4[lane + 64];
    float4 o0, o1;
    o0.x = 0.5f * (q0.x + a0.x); o0.y = 0.5f * (q0.y + a0.y);
    o0.z = 0.5f * (q0.z + a0.z); o0.w = 0.5f * (q0.w + a0.w);
    o1.x = 0.5f * (q1.x + a1.x); o1.y = 0.5f * (q1.y + a1.y);
    o1.z = 0.5f * (q1.z + a1.z); o1.w = 0.5f * (q1.w + a1.w);
    float4* out4 = (float4*)(outk + ((size_t)(b * CC) + c) * DD);
    out4[lane]      = o0;
    out4[lane + 64] = o1;
}

// ---------------------------------------------------------------- launch
extern "C" void kernel_launch(void* const* d_in, const int* in_sizes, int n_in,
                              void* d_out, int out_size, void* d_ws, size_t ws_size,
                              hipStream_t stream) {
    const float* Q  = (const float*)d_in[0];
    const float* I  = (const float*)d_in[1];
    const float* KN = (const float*)d_in[2];
    const int* ilab = (const int*)d_in[3];
    const int* klab = (const int*)d_in[4];

    char* ws = (char*)d_ws;
    float* S        = (float*)ws;  ws += (size_t)BB * NIMG * 4;
    int*   img_list = (int*)ws;    ws += (size_t)CC * NIMG * 4;
    int*   kn_list  = (int*)ws;    ws += (size_t)CC * NKN * 4;
    int*   t_idx    = (int*)ws;    ws += (size_t)BB * CC * RR * 4;
    float* t_w      = (float*)ws;  ws += (size_t)BB * CC * RR * 4;
    int*   img_cnt  = (int*)ws;    ws += CC * 4;
    int*   kn_cnt   = (int*)ws;    ws += CC * 4;

    float* out_img = (float*)d_out;
    float* out_kn  = out_img + (size_t)BB * CC * DD;

    hipMemsetAsync(img_cnt, 0, 2 * CC * 4, stream);  // img_cnt + kn_cnt contiguous

    build_lists<<<(NIMG + 255) / 256, 256, 0, stream>>>(ilab, NIMG, img_cnt, img_list, NIMG);
    build_lists<<<(NKN  + 255) / 256, 256, 0, stream>>>(klab, NKN,  kn_cnt,  kn_list,  NKN);
    sims_kernel<<<(NIMG + 255) / 256, 256, 0, stream>>>(Q, I, S);
    topk_img<<<dim3(CC, BB), 256, 0, stream>>>(S, img_cnt, img_list, t_idx, t_w);
    img_kernel<<<dim3(CC, BB), 256, 0, stream>>>(Q, I, t_idx, t_w, (float*)d_out);
    knowledge_kernel<<<dim3(CC, BB), 64, 0, stream>>>(Q, I, KN, kn_cnt, kn_list, t_idx, t_w, out_kn);
}